// Round 4
// baseline (517.442 us; speedup 1.0000x reference)
//
#include <hip/hip_runtime.h>

#define THREADS 256
#define NROWS 2097152            // 128 * 16384 timestep rows
#define BLOCKS (NROWS / THREADS) // 8192
#define DT 0.005f
#define INV_HUBER 200.0f         // 1/0.005

#define NELEM 6291456.0          // 128*16384*3
#define CNT16 391296.0           // 128*1019*3
#define CNT32 194688.0           // 128*507*3

// Rodrigues: R = I + st*W + ct*(phi phi^T - a2 I)
__device__ __forceinline__ void so3_exp3(float x, float y, float z, float R[9]) {
    float a2 = x * x + y * y + z * z;
    bool sm = a2 < 1e-12f;
    float a2s = sm ? 1.0f : a2;
    float a = sqrtf(a2s);
    float s = sinf(a);
    float c = cosf(a);
    float st = sm ? (1.0f - a2 * (1.0f / 6.0f)) : (s / a);
    float ct = sm ? (0.5f - a2 * (1.0f / 24.0f)) : ((1.0f - c) / a2s);
    R[0] = 1.0f + ct * (x * x - a2);
    R[1] = ct * (x * y) - st * z;
    R[2] = ct * (x * z) + st * y;
    R[3] = ct * (x * y) + st * z;
    R[4] = 1.0f + ct * (y * y - a2);
    R[5] = ct * (y * z) - st * x;
    R[6] = ct * (x * z) - st * y;
    R[7] = ct * (y * z) + st * x;
    R[8] = 1.0f + ct * (z * z - a2);
}

__device__ __forceinline__ void mm3(const float A[9], const float B[9], float C[9]) {
#pragma unroll
    for (int i = 0; i < 3; ++i) {
        float a0 = A[3 * i], a1 = A[3 * i + 1], a2 = A[3 * i + 2];
        C[3 * i + 0] = a0 * B[0] + a1 * B[3] + a2 * B[6];
        C[3 * i + 1] = a0 * B[1] + a1 * B[4] + a2 * B[7];
        C[3 * i + 2] = a0 * B[2] + a1 * B[5] + a2 * B[8];
    }
}

// sum of huber( so3_log(A^T B) / HUBER ) over the 3 components
__device__ __forceinline__ float huber_bmtm(const float A[9], const float B[9]) {
    float tr = 0.f, w0 = 0.f, w1 = 0.f, w2 = 0.f;
#pragma unroll
    for (int k = 0; k < 3; ++k) {
        float a0 = A[3 * k], a1 = A[3 * k + 1], a2v = A[3 * k + 2];
        float b0 = B[3 * k], b1 = B[3 * k + 1], b2v = B[3 * k + 2];
        tr += a0 * b0 + a1 * b1 + a2v * b2v;   // trace(A^T B)
        w0 += a2v * b1 - a1 * b2v;             // M[2][1]-M[1][2]
        w1 += a0 * b2v - a2v * b0;             // M[0][2]-M[2][0]
        w2 += a1 * b0 - a0 * b1;               // M[1][0]-M[0][1]
    }
    float cs = 0.5f * (tr - 1.0f);
    cs = fminf(fmaxf(cs, -1.0f + 1e-6f), 1.0f - 1e-6f);
    float ang = acosf(cs);
    float fac = ang / (2.0f * sinf(ang));      // clamp => ang >= ~1.4e-3, no small branch
    float h = 0.0f, r;
    r = fabsf(fac * w0 * INV_HUBER); h += (r < 1.0f) ? 0.5f * r * r : (r - 0.5f);
    r = fabsf(fac * w1 * INV_HUBER); h += (r < 1.0f) ? 0.5f * r * r : (r - 0.5f);
    r = fabsf(fac * w2 * INV_HUBER); h += (r < 1.0f) ? 0.5f * r * r : (r - 0.5f);
    return h;
}

__global__ __launch_bounds__(THREADS) void dg_loss_kernel(
    const float* __restrict__ w_hat, const float* __restrict__ dw16,
    const float* __restrict__ w_gt, const float* __restrict__ w_mean,
    const float* __restrict__ w_std, float* __restrict__ out,
    double* acc, unsigned int* counter)
{
    const int r = blockIdx.x * THREADS + threadIdx.x;   // timestep row, 0..NROWS-1
    const int lane = threadIdx.x & 63;

    // ---- load own row of all 4 elementwise arrays (w_hat used by BOTH losses) ----
    const size_t o = (size_t)r * 3;
    const float h0 = w_hat[o], h1 = w_hat[o + 1], h2 = w_hat[o + 2];
    const float g0 = w_gt[o], g1 = w_gt[o + 1], g2 = w_gt[o + 2];
    const float m0 = w_mean[o], m1 = w_mean[o + 1], m2 = w_mean[o + 2];
    const float s0 = w_std[o], s1 = w_std[o + 1], s2 = w_std[o + 2];

    // ---- gaussian NLL for this row ----
    double lg;
    {
        float v = fmaxf(s0 * s0, 1e-6f); float d = g0 - h0 - m0;
        float p = logf(v) + d * d / v;
        v = fmaxf(s1 * s1, 1e-6f); d = g1 - h1 - m1;
        p += logf(v) + d * d / v;
        v = fmaxf(s2 * s2, 1e-6f); d = g2 - h2 - m2;
        p += logf(v) + d * d / v;
        lg = 0.5 * (double)p;
    }

    // ---- gyro: butterfly product tree over 16-lane groups ----
    float P[9];
    so3_exp3(DT * h0, DT * h1, DT * h2, P);
#pragma unroll
    for (int s = 1; s <= 8; s <<= 1) {
        float Nb[9];
#pragma unroll
        for (int e = 0; e < 9; ++e) Nb[e] = __shfl_xor(P[e], s);
        const bool rt = (lane & s) != 0;    // right half of the 2s segment
        float A[9], B[9], T[9];
#pragma unroll
        for (int e = 0; e < 9; ++e) { A[e] = rt ? Nb[e] : P[e]; B[e] = rt ? P[e] : Nb[e]; }
        mm3(A, B, T);
#pragma unroll
        for (int e = 0; e < 9; ++e) P[e] = T[e];
    }
    // P = ordered product of exp(DT*w_hat) over this 16-row block (same balanced
    // association as the reference's repeated _pairwise)

    // Q16 = exp(dw16[row 16*b]); every lane of the group computes it (broadcast load)
    const int b = r >> 4;                       // global 16-block index
    const size_t qo = (size_t)b * 48;
    float Q[9];
    {
        const float q0 = dw16[qo], q1 = dw16[qo + 1], q2 = dw16[qo + 2];
        so3_exp3(q0, q1, q2, Q);
    }

    double lh16 = 0.0, lh32 = 0.0;
    const int sub = lane & 15;
    if (sub == 0 && ((b & 1023) >= 5))          // skip first N0=5 16-blocks per trajectory
        lh16 = (double)huber_bmtm(P, Q);

    // ---- 32-level: combine adjacent 16-groups (within wave) ----
    float Pn[9], Qn[9];
#pragma unroll
    for (int e = 0; e < 9; ++e) {
        Pn[e] = __shfl_xor(P[e], 16);
        Qn[e] = __shfl_xor(Q[e], 16);
    }
    if ((lane & 31) == 0) {                     // lanes 0 and 32: left (even) groups
        const int c = r >> 5;                   // global 32-block index
        if ((c & 511) >= 5) {
            float P32[9], Q32[9];
            mm3(P, Pn, P32);
            mm3(Q, Qn, Q32);
            lh32 = (double)huber_bmtm(P32, Q32);
        }
    }

    // ---- block reduction (3 doubles) ----
    __shared__ double s_g[4], s_h16[4], s_h32[4];
#pragma unroll
    for (int off = 32; off > 0; off >>= 1) {
        lg += __shfl_down(lg, off);
        lh16 += __shfl_down(lh16, off);
        lh32 += __shfl_down(lh32, off);
    }
    const int wv = threadIdx.x >> 6;
    if (lane == 0) { s_g[wv] = lg; s_h16[wv] = lh16; s_h32[wv] = lh32; }
    __syncthreads();
    if (threadIdx.x == 0) {
        double g = s_g[0] + s_g[1] + s_g[2] + s_g[3];
        double h16 = s_h16[0] + s_h16[1] + s_h16[2] + s_h16[3];
        double h32 = s_h32[0] + s_h32[1] + s_h32[2] + s_h32[3];
        atomicAdd(&acc[0], g);
        atomicAdd(&acc[1], h16);
        atomicAdd(&acc[2], h32);
        __threadfence();
        unsigned prev = atomicAdd(counter, 1u);
        if (prev == BLOCKS - 1) {
            double ga = atomicAdd(&acc[0], 0.0);
            double h16a = atomicAdd(&acc[1], 0.0);
            double h32a = atomicAdd(&acc[2], 0.0);
            // gyro16 = 25*mean16 ; gyro32 = 25*mean32/4 ; gnll = mean
            out[0] = (float)(25.0 * (h16a / CNT16) + 6.25 * (h32a / CNT32) + ga / NELEM);
        }
    }
}

extern "C" void kernel_launch(void* const* d_in, const int* in_sizes, int n_in,
                              void* d_out, int out_size, void* d_ws, size_t ws_size,
                              hipStream_t stream) {
    const float* w_hat = (const float*)d_in[0];
    const float* dw16 = (const float*)d_in[1];
    const float* w_gt = (const float*)d_in[2];
    const float* w_mean = (const float*)d_in[3];
    const float* w_std = (const float*)d_in[4];
    float* out = (float*)d_out;

    double* acc = (double*)d_ws;                       // acc[0..2]
    unsigned int* counter = (unsigned int*)((char*)d_ws + 24);

    hipMemsetAsync(d_ws, 0, 32, stream);               // zero accumulators + counter
    dg_loss_kernel<<<BLOCKS, THREADS, 0, stream>>>(
        w_hat, dw16, w_gt, w_mean, w_std, out, acc, counter);
}

// Round 5
// 162.523 us; speedup vs baseline: 3.1838x; 3.1838x over previous
//
#include <hip/hip_runtime.h>

#define THREADS 256
#define NROWS 2097152            // 128 * 16384 timestep rows
#define BLOCKS (NROWS / THREADS) // 8192
#define DT 0.005f
#define INV_HUBER 200.0f         // 1/0.005

#define NELEM 6291456.0          // 128*16384*3
#define CNT16 391296.0           // 128*1019*3
#define CNT32 194688.0           // 128*507*3

// Rodrigues: R = I + st*W + ct*(phi phi^T - a2 I)
__device__ __forceinline__ void so3_exp3(float x, float y, float z, float R[9]) {
    float a2 = x * x + y * y + z * z;
    bool sm = a2 < 1e-12f;
    float a2s = sm ? 1.0f : a2;
    float a = sqrtf(a2s);
    float s = sinf(a);
    float c = cosf(a);
    float st = sm ? (1.0f - a2 * (1.0f / 6.0f)) : (s / a);
    float ct = sm ? (0.5f - a2 * (1.0f / 24.0f)) : ((1.0f - c) / a2s);
    R[0] = 1.0f + ct * (x * x - a2);
    R[1] = ct * (x * y) - st * z;
    R[2] = ct * (x * z) + st * y;
    R[3] = ct * (x * y) + st * z;
    R[4] = 1.0f + ct * (y * y - a2);
    R[5] = ct * (y * z) - st * x;
    R[6] = ct * (x * z) - st * y;
    R[7] = ct * (y * z) + st * x;
    R[8] = 1.0f + ct * (z * z - a2);
}

__device__ __forceinline__ void mm3(const float A[9], const float B[9], float C[9]) {
#pragma unroll
    for (int i = 0; i < 3; ++i) {
        float a0 = A[3 * i], a1 = A[3 * i + 1], a2 = A[3 * i + 2];
        C[3 * i + 0] = a0 * B[0] + a1 * B[3] + a2 * B[6];
        C[3 * i + 1] = a0 * B[1] + a1 * B[4] + a2 * B[7];
        C[3 * i + 2] = a0 * B[2] + a1 * B[5] + a2 * B[8];
    }
}

// sum of huber( so3_log(A^T B) / HUBER ) over the 3 components
__device__ __forceinline__ float huber_bmtm(const float A[9], const float B[9]) {
    float tr = 0.f, w0 = 0.f, w1 = 0.f, w2 = 0.f;
#pragma unroll
    for (int k = 0; k < 3; ++k) {
        float a0 = A[3 * k], a1 = A[3 * k + 1], a2v = A[3 * k + 2];
        float b0 = B[3 * k], b1 = B[3 * k + 1], b2v = B[3 * k + 2];
        tr += a0 * b0 + a1 * b1 + a2v * b2v;   // trace(A^T B)
        w0 += a2v * b1 - a1 * b2v;             // M[2][1]-M[1][2]
        w1 += a0 * b2v - a2v * b0;             // M[0][2]-M[2][0]
        w2 += a1 * b0 - a0 * b1;               // M[1][0]-M[0][1]
    }
    float cs = 0.5f * (tr - 1.0f);
    cs = fminf(fmaxf(cs, -1.0f + 1e-6f), 1.0f - 1e-6f);
    float ang = acosf(cs);
    float sn = sqrtf(fmaxf(1.0f - cs * cs, 0.0f));   // sin(acos(cs)), ang in [0,pi]
    float fac = ang / (2.0f * sn);
    float h = 0.0f, r;
    r = fabsf(fac * w0 * INV_HUBER); h += (r < 1.0f) ? 0.5f * r * r : (r - 0.5f);
    r = fabsf(fac * w1 * INV_HUBER); h += (r < 1.0f) ? 0.5f * r * r : (r - 0.5f);
    r = fabsf(fac * w2 * INV_HUBER); h += (r < 1.0f) ? 0.5f * r * r : (r - 0.5f);
    return h;
}

__global__ __launch_bounds__(THREADS) void dg_loss_kernel(
    const float* __restrict__ w_hat, const float* __restrict__ dw16,
    const float* __restrict__ w_gt, const float* __restrict__ w_mean,
    const float* __restrict__ w_std, double* __restrict__ partial)
{
    const int r = blockIdx.x * THREADS + threadIdx.x;   // timestep row, 0..NROWS-1
    const int lane = threadIdx.x & 63;

    // ---- load own row of all 4 elementwise arrays (w_hat used by BOTH losses) ----
    const size_t o = (size_t)r * 3;
    const float h0 = w_hat[o], h1 = w_hat[o + 1], h2 = w_hat[o + 2];
    const float g0 = w_gt[o], g1 = w_gt[o + 1], g2 = w_gt[o + 2];
    const float m0 = w_mean[o], m1 = w_mean[o + 1], m2 = w_mean[o + 2];
    const float s0 = w_std[o], s1 = w_std[o + 1], s2 = w_std[o + 2];

    // ---- gaussian NLL for this row ----
    double lg;
    {
        float v = fmaxf(s0 * s0, 1e-6f); float d = g0 - h0 - m0;
        float p = logf(v) + d * d / v;
        v = fmaxf(s1 * s1, 1e-6f); d = g1 - h1 - m1;
        p += logf(v) + d * d / v;
        v = fmaxf(s2 * s2, 1e-6f); d = g2 - h2 - m2;
        p += logf(v) + d * d / v;
        lg = 0.5 * (double)p;
    }

    // ---- gyro: butterfly product tree over 16-lane groups ----
    float P[9];
    so3_exp3(DT * h0, DT * h1, DT * h2, P);
#pragma unroll
    for (int s = 1; s <= 8; s <<= 1) {
        float Nb[9];
#pragma unroll
        for (int e = 0; e < 9; ++e) Nb[e] = __shfl_xor(P[e], s);
        const bool rt = (lane & s) != 0;    // right half of the 2s segment
        float A[9], B[9], T[9];
#pragma unroll
        for (int e = 0; e < 9; ++e) { A[e] = rt ? Nb[e] : P[e]; B[e] = rt ? P[e] : Nb[e]; }
        mm3(A, B, T);
#pragma unroll
        for (int e = 0; e < 9; ++e) P[e] = T[e];
    }
    // P = ordered product of exp(DT*w_hat) over this 16-row block (same balanced
    // association as the reference's repeated _pairwise)

    // Q16 = exp(dw16[row 16*b]); every lane of the group computes it (broadcast load)
    const int b = r >> 4;                       // global 16-block index
    const size_t qo = (size_t)b * 48;
    float Q[9];
    {
        const float q0 = dw16[qo], q1 = dw16[qo + 1], q2 = dw16[qo + 2];
        so3_exp3(q0, q1, q2, Q);
    }

    double lh16 = 0.0, lh32 = 0.0;
    const int sub = lane & 15;
    if (sub == 0 && ((b & 1023) >= 5))          // skip first N0=5 16-blocks per trajectory
        lh16 = (double)huber_bmtm(P, Q);

    // ---- 32-level: combine adjacent 16-groups (within wave) ----
    float Pn[9], Qn[9];
#pragma unroll
    for (int e = 0; e < 9; ++e) {
        Pn[e] = __shfl_xor(P[e], 16);
        Qn[e] = __shfl_xor(Q[e], 16);
    }
    if ((lane & 31) == 0) {                     // lanes 0 and 32: left (even) groups
        const int c = r >> 5;                   // global 32-block index
        if ((c & 511) >= 5) {
            float P32[9], Q32[9];
            mm3(P, Pn, P32);
            mm3(Q, Qn, Q32);
            lh32 = (double)huber_bmtm(P32, Q32);
        }
    }

    // ---- block reduction: pre-scaled single double, plain store (NO atomics) ----
    double part = lg * (1.0 / NELEM) + lh16 * (25.0 / CNT16) + lh32 * (6.25 / CNT32);
    __shared__ double s_p[4];
#pragma unroll
    for (int off = 32; off > 0; off >>= 1)
        part += __shfl_down(part, off);
    const int wv = threadIdx.x >> 6;
    if (lane == 0) s_p[wv] = part;
    __syncthreads();
    if (threadIdx.x == 0)
        partial[blockIdx.x] = s_p[0] + s_p[1] + s_p[2] + s_p[3];
}

__global__ __launch_bounds__(THREADS) void finalize_kernel(
    const double* __restrict__ partial, float* __restrict__ out)
{
    double s = 0.0;
#pragma unroll
    for (int i = 0; i < BLOCKS / THREADS; ++i)          // 32 strided loads each
        s += partial[i * THREADS + threadIdx.x];
    __shared__ double s_p[4];
#pragma unroll
    for (int off = 32; off > 0; off >>= 1)
        s += __shfl_down(s, off);
    const int lane = threadIdx.x & 63, wv = threadIdx.x >> 6;
    if (lane == 0) s_p[wv] = s;
    __syncthreads();
    if (threadIdx.x == 0)
        out[0] = (float)(s_p[0] + s_p[1] + s_p[2] + s_p[3]);
}

extern "C" void kernel_launch(void* const* d_in, const int* in_sizes, int n_in,
                              void* d_out, int out_size, void* d_ws, size_t ws_size,
                              hipStream_t stream) {
    const float* w_hat = (const float*)d_in[0];
    const float* dw16 = (const float*)d_in[1];
    const float* w_gt = (const float*)d_in[2];
    const float* w_mean = (const float*)d_in[3];
    const float* w_std = (const float*)d_in[4];
    float* out = (float*)d_out;
    double* partial = (double*)d_ws;                   // BLOCKS doubles = 64 KB

    dg_loss_kernel<<<BLOCKS, THREADS, 0, stream>>>(
        w_hat, dw16, w_gt, w_mean, w_std, partial);
    finalize_kernel<<<1, THREADS, 0, stream>>>(partial, out);
}

// Round 6
// 146.647 us; speedup vs baseline: 3.5285x; 1.1083x over previous
//
#include <hip/hip_runtime.h>

#define THREADS 256
#define NQUAD 524288             // 2097152 rows / 4 rows per thread
#define BLOCKS (NQUAD / THREADS) // 2048
#define DT 0.005f
#define INV_HUBER 200.0f         // 1/0.005

#define NELEM 6291456.0          // 128*16384*3
#define CNT16 391296.0           // 128*1019*3
#define CNT32 194688.0           // 128*507*3

// Rodrigues, small-angle (|phi| <= ~0.04): Taylor st/ct, error ~4e-13 rel
__device__ __forceinline__ void so3_exp_small(float x, float y, float z, float R[9]) {
    float a2 = x * x + y * y + z * z;
    float st = 1.0f - a2 * (1.0f / 6.0f) * (1.0f - a2 * (1.0f / 20.0f));   // 1 - a2/6 + a4/120
    float ct = 0.5f - a2 * (1.0f / 24.0f) * (1.0f - a2 * (1.0f / 30.0f));  // 1/2 - a2/24 + a4/720
    R[0] = 1.0f + ct * (x * x - a2);
    R[1] = ct * (x * y) - st * z;
    R[2] = ct * (x * z) + st * y;
    R[3] = ct * (x * y) + st * z;
    R[4] = 1.0f + ct * (y * y - a2);
    R[5] = ct * (y * z) - st * x;
    R[6] = ct * (x * z) - st * y;
    R[7] = ct * (y * z) + st * x;
    R[8] = 1.0f + ct * (z * z - a2);
}

// Rodrigues, full range (dw16 angles up to ~6 rad)
__device__ __forceinline__ void so3_exp_full(float x, float y, float z, float R[9]) {
    float a2 = x * x + y * y + z * z;
    bool sm = a2 < 1e-12f;
    float a2s = sm ? 1.0f : a2;
    float a = sqrtf(a2s);
    float s, c;
    sincosf(a, &s, &c);
    float st = sm ? (1.0f - a2 * (1.0f / 6.0f)) : (s / a);
    float ct = sm ? (0.5f - a2 * (1.0f / 24.0f)) : ((1.0f - c) / a2s);
    R[0] = 1.0f + ct * (x * x - a2);
    R[1] = ct * (x * y) - st * z;
    R[2] = ct * (x * z) + st * y;
    R[3] = ct * (x * y) + st * z;
    R[4] = 1.0f + ct * (y * y - a2);
    R[5] = ct * (y * z) - st * x;
    R[6] = ct * (x * z) - st * y;
    R[7] = ct * (y * z) + st * x;
    R[8] = 1.0f + ct * (z * z - a2);
}

__device__ __forceinline__ void mm3(const float A[9], const float B[9], float C[9]) {
#pragma unroll
    for (int i = 0; i < 3; ++i) {
        float a0 = A[3 * i], a1 = A[3 * i + 1], a2 = A[3 * i + 2];
        C[3 * i + 0] = a0 * B[0] + a1 * B[3] + a2 * B[6];
        C[3 * i + 1] = a0 * B[1] + a1 * B[4] + a2 * B[7];
        C[3 * i + 2] = a0 * B[2] + a1 * B[5] + a2 * B[8];
    }
}

// sum of huber( so3_log(A^T B) / HUBER ) over the 3 components
__device__ __forceinline__ float huber_bmtm(const float A[9], const float B[9]) {
    float tr = 0.f, w0 = 0.f, w1 = 0.f, w2 = 0.f;
#pragma unroll
    for (int k = 0; k < 3; ++k) {
        float a0 = A[3 * k], a1 = A[3 * k + 1], a2v = A[3 * k + 2];
        float b0 = B[3 * k], b1 = B[3 * k + 1], b2v = B[3 * k + 2];
        tr += a0 * b0 + a1 * b1 + a2v * b2v;   // trace(A^T B)
        w0 += a2v * b1 - a1 * b2v;
        w1 += a0 * b2v - a2v * b0;
        w2 += a1 * b0 - a0 * b1;
    }
    float cs = 0.5f * (tr - 1.0f);
    cs = fminf(fmaxf(cs, -1.0f + 1e-6f), 1.0f - 1e-6f);
    float ang = acosf(cs);
    float sn = sqrtf(fmaxf(1.0f - cs * cs, 0.0f));   // sin(acos(cs)), ang in [0,pi]
    float fac = ang / (2.0f * sn);
    float h = 0.0f, r;
    r = fabsf(fac * w0 * INV_HUBER); h += (r < 1.0f) ? 0.5f * r * r : (r - 0.5f);
    r = fabsf(fac * w1 * INV_HUBER); h += (r < 1.0f) ? 0.5f * r * r : (r - 0.5f);
    r = fabsf(fac * w2 * INV_HUBER); h += (r < 1.0f) ? 0.5f * r * r : (r - 0.5f);
    return h;
}

// gaussian NLL partial for 4 consecutive elements (row-agnostic, elementwise)
__device__ __forceinline__ float gnll4(float4 h, float4 g, float4 m, float4 s) {
    float p = 0.f;
#pragma unroll
    for (int k = 0; k < 4; ++k) {
        float hv = (&h.x)[k], gv = (&g.x)[k], mv = (&m.x)[k], sv = (&s.x)[k];
        float v = fmaxf(sv * sv, 1e-6f);
        float d = gv - hv - mv;
        float rv = __builtin_amdgcn_rcpf(v);
        rv = rv * (2.0f - v * rv);                   // 1 Newton step, ~1e-7 rel
        p += __logf(v) + d * d * rv;
    }
    return p;
}

__global__ __launch_bounds__(THREADS) void dg_loss_kernel(
    const float* __restrict__ w_hat, const float* __restrict__ dw16,
    const float* __restrict__ w_gt, const float* __restrict__ w_mean,
    const float* __restrict__ w_std, double* __restrict__ partial)
{
    const int t = blockIdx.x * THREADS + threadIdx.x;   // quad-row index, 0..NQUAD-1
    const int lane = threadIdx.x & 63;

    // ---- vector loads: 4 rows = 12 floats = 3 float4 per array (16B aligned) ----
    const float4* hp = (const float4*)w_hat + (size_t)t * 3;
    const float4* gp = (const float4*)w_gt + (size_t)t * 3;
    const float4* mp = (const float4*)w_mean + (size_t)t * 3;
    const float4* sp = (const float4*)w_std + (size_t)t * 3;
    const int b = t >> 2;                               // global 16-block index
    float4 q4 = ((const float4*)dw16)[(size_t)b * 12];  // dw16 row 16*b (broadcast in group)

    float4 h0 = hp[0], h1 = hp[1], h2 = hp[2];
    float4 g0 = gp[0], g1 = gp[1], g2 = gp[2];
    float4 m0 = mp[0], m1 = mp[1], m2 = mp[2];
    float4 s0 = sp[0], s1 = sp[1], s2 = sp[2];

    // ---- gaussian NLL over this thread's 12 elements ----
    double lg = 0.5 * (double)(gnll4(h0, g0, m0, s0) + gnll4(h1, g1, m1, s1) + gnll4(h2, g2, m2, s2));

    // ---- in-lane: 4 exps + balanced 3-mm3 tree (matches reference association) ----
    float E0[9], E1[9], E2[9], E3[9], T01[9], T23[9], P[9];
    so3_exp_small(DT * h0.x, DT * h0.y, DT * h0.z, E0);
    so3_exp_small(DT * h0.w, DT * h1.x, DT * h1.y, E1);
    so3_exp_small(DT * h1.z, DT * h1.w, DT * h2.x, E2);
    so3_exp_small(DT * h2.y, DT * h2.z, DT * h2.w, E3);
    mm3(E0, E1, T01);
    mm3(E2, E3, T23);
    mm3(T01, T23, P);                                   // product of my 4 rows

    // ---- butterfly over 4-lane groups: strides 1,2 -> ordered 16-row product ----
#pragma unroll
    for (int s = 1; s <= 2; s <<= 1) {
        float Nb[9];
#pragma unroll
        for (int e = 0; e < 9; ++e) Nb[e] = __shfl_xor(P[e], s);
        const bool rt = (lane & s) != 0;
        float A[9], B[9], T[9];
#pragma unroll
        for (int e = 0; e < 9; ++e) { A[e] = rt ? Nb[e] : P[e]; B[e] = rt ? P[e] : Nb[e]; }
        mm3(A, B, T);
#pragma unroll
        for (int e = 0; e < 9; ++e) P[e] = T[e];
    }

    // Q16 = exp(dw16 row) — 4x redundant per group (branch-free)
    float Q[9];
    so3_exp_full(q4.x, q4.y, q4.z, Q);

    double lh16 = 0.0, lh32 = 0.0;
    if ((lane & 3) == 0 && ((b & 1023) >= 5))           // skip first N0=5 16-blocks / traj
        lh16 = (double)huber_bmtm(P, Q);

    // ---- 32-level: combine adjacent 16-groups (stride-4 xor within wave) ----
    float Pn[9], Qn[9];
#pragma unroll
    for (int e = 0; e < 9; ++e) {
        Pn[e] = __shfl_xor(P[e], 4);
        Qn[e] = __shfl_xor(Q[e], 4);
    }
    if ((lane & 7) == 0) {                              // even 16-group leader
        const int c = t >> 3;                           // global 32-block index
        if ((c & 511) >= 5) {
            float P32[9], Q32[9];
            mm3(P, Pn, P32);
            mm3(Q, Qn, Q32);
            lh32 = (double)huber_bmtm(P32, Q32);
        }
    }

    // ---- block reduction: pre-scaled single double, plain store (no atomics) ----
    double part = lg * (1.0 / NELEM) + lh16 * (25.0 / CNT16) + lh32 * (6.25 / CNT32);
    __shared__ double s_p[4];
#pragma unroll
    for (int off = 32; off > 0; off >>= 1)
        part += __shfl_down(part, off);
    const int wv = threadIdx.x >> 6;
    if (lane == 0) s_p[wv] = part;
    __syncthreads();
    if (threadIdx.x == 0)
        partial[blockIdx.x] = s_p[0] + s_p[1] + s_p[2] + s_p[3];
}

__global__ __launch_bounds__(THREADS) void finalize_kernel(
    const double* __restrict__ partial, float* __restrict__ out)
{
    double s = 0.0;
#pragma unroll
    for (int i = 0; i < BLOCKS / THREADS; ++i)          // 8 strided loads each
        s += partial[i * THREADS + threadIdx.x];
    __shared__ double s_p[4];
#pragma unroll
    for (int off = 32; off > 0; off >>= 1)
        s += __shfl_down(s, off);
    const int lane = threadIdx.x & 63, wv = threadIdx.x >> 6;
    if (lane == 0) s_p[wv] = s;
    __syncthreads();
    if (threadIdx.x == 0)
        out[0] = (float)(s_p[0] + s_p[1] + s_p[2] + s_p[3]);
}

extern "C" void kernel_launch(void* const* d_in, const int* in_sizes, int n_in,
                              void* d_out, int out_size, void* d_ws, size_t ws_size,
                              hipStream_t stream) {
    const float* w_hat = (const float*)d_in[0];
    const float* dw16 = (const float*)d_in[1];
    const float* w_gt = (const float*)d_in[2];
    const float* w_mean = (const float*)d_in[3];
    const float* w_std = (const float*)d_in[4];
    float* out = (float*)d_out;
    double* partial = (double*)d_ws;                   // BLOCKS doubles = 16 KB

    dg_loss_kernel<<<BLOCKS, THREADS, 0, stream>>>(
        w_hat, dw16, w_gt, w_mean, w_std, partial);
    finalize_kernel<<<1, THREADS, 0, stream>>>(partial, out);
}